// Round 6
// baseline (272.424 us; speedup 1.0000x reference)
//
#include <hip/hip_runtime.h>

#define F_DIM  256
#define ELLK   64      // tier-1 slots per row (8 segs x 8)
#define SEGS   8
#define SEGCAP 8
#define T2CAP  8       // tier-2 slots per row
#define OVFCAP 4096

struct OvfEdge { int r, c; float v; };

__device__ __forceinline__ unsigned short f32_to_bf16(float x) {
    unsigned u = __float_as_uint(x);
    unsigned r = (u + 0x7FFFu + ((u >> 16) & 1u)) >> 16;  // RNE
    return (unsigned short)r;
}

__device__ __forceinline__ unsigned pack_edge(int c, float v) {
    return ((unsigned)c << 16) | f32_to_bf16(v);
}

// ---------- mat_2 f32 -> bf16, 4 elems/thread ----------
__global__ void cvt_kernel(const float* __restrict__ src,
                           unsigned short* __restrict__ dst, int n4) {
    int t = blockIdx.x * blockDim.x + threadIdx.x;
    if (t >= n4) return;
    float4 f = ((const float4*)src)[t];
    ushort4 o;
    o.x = f32_to_bf16(f.x); o.y = f32_to_bf16(f.y);
    o.z = f32_to_bf16(f.z); o.w = f32_to_bf16(f.w);
    ((ushort4*)dst)[t] = o;
}

// ---------- Path A: XCD-segmented single-pass ELL build ----------
__device__ __forceinline__ void scatter_seg_one(int r, int c, float v, int seg, int N,
                                                int* cur8, int* t2cur,
                                                unsigned* ell1, unsigned* ell2,
                                                int* ovfcnt, OvfEdge* ovf) {
    int pos = atomicAdd(&cur8[seg * N + r], 1);
    if (pos < SEGCAP) {
        ell1[((long long)r << 6) | (seg << 3) | pos] = pack_edge(c, v);
    } else {
        int p2 = atomicAdd(&t2cur[r], 1);
        if (p2 < T2CAP) {
            ell2[(r << 3) | p2] = pack_edge(c, v);
        } else {
            int o = atomicAdd(ovfcnt, 1);
            if (o < OVFCAP) { ovf[o].r = r; ovf[o].c = c; ovf[o].v = v; }
        }
    }
}

__global__ void scatter_seg_kernel(const int* __restrict__ rows,
                                   const int* __restrict__ cols,
                                   const float* __restrict__ vals,
                                   int* __restrict__ cur8,
                                   int* __restrict__ t2cur,
                                   unsigned* __restrict__ ell1,
                                   unsigned* __restrict__ ell2,
                                   int* __restrict__ ovfcnt,
                                   OvfEdge* __restrict__ ovf, int E, int N) {
    int seg = blockIdx.x & (SEGS - 1);   // ~XCD id under default round-robin dispatch
    int t = blockIdx.x * blockDim.x + threadIdx.x;
    int i0 = t * 4;
    if (i0 + 3 < E) {
        int4   r = *(const int4*)(rows + i0);
        int4   c = *(const int4*)(cols + i0);
        float4 v = *(const float4*)(vals + i0);
        scatter_seg_one(r.x, c.x, v.x, seg, N, cur8, t2cur, ell1, ell2, ovfcnt, ovf);
        scatter_seg_one(r.y, c.y, v.y, seg, N, cur8, t2cur, ell1, ell2, ovfcnt, ovf);
        scatter_seg_one(r.z, c.z, v.z, seg, N, cur8, t2cur, ell1, ell2, ovfcnt, ovf);
        scatter_seg_one(r.w, c.w, v.w, seg, N, cur8, t2cur, ell1, ell2, ovfcnt, ovf);
    } else {
        for (int i = i0; i < E; ++i)
            scatter_seg_one(rows[i], cols[i], vals[i], seg, N, cur8, t2cur, ell1, ell2, ovfcnt, ovf);
    }
}

__device__ __forceinline__ void gfma(unsigned e, int lane,
                                     const unsigned short* __restrict__ mb, float4& acc) {
    int   col = (int)(e >> 16);
    float v   = __uint_as_float((e & 0xFFFFu) << 16);
    ushort4 m = ((const ushort4*)(mb + ((long long)col << 8)))[lane];
    acc.x += v * __uint_as_float((unsigned)m.x << 16);
    acc.y += v * __uint_as_float((unsigned)m.y << 16);
    acc.z += v * __uint_as_float((unsigned)m.z << 16);
    acc.w += v * __uint_as_float((unsigned)m.w << 16);
}

// ---------- Path A SpMM: one wave per row, lane-compacted segments ----------
__global__ void __launch_bounds__(256)
spmm_seg_kernel(const int* __restrict__ cur8,
                const int* __restrict__ t2cur,
                const unsigned* __restrict__ ell1,
                const unsigned* __restrict__ ell2,
                const unsigned short* __restrict__ mb,
                float* __restrict__ out, int N) {
    int wave = (int)(((long long)blockIdx.x * blockDim.x + threadIdx.x) >> 6);
    int lane = threadIdx.x & 63;
    if (wave >= N) return;
    const int r = wave;

    int sc  = (lane < SEGS) ? cur8[lane * N + r] : 0;
    int t2l = (lane == SEGS) ? t2cur[r] : 0;

    int segcnt = min(__shfl(sc, lane >> 3), SEGCAP);
    bool valid = (lane & 7) < segcnt;
    unsigned pk = valid ? ell1[((long long)r << 6) | lane] : 0u;

    unsigned long long mask = __ballot(valid);
    int total = __popcll(mask);
    int below = __popcll(mask & ((1ull << lane) - 1ull));
    int dst = valid ? below : (total + (lane - below));
    unsigned pkc = (unsigned)__builtin_amdgcn_ds_permute(dst << 2, (int)pk);

    float4 acc = make_float4(0.f, 0.f, 0.f, 0.f);
    int padded = (total + 7) & ~7;
    for (int j = 0; j < padded; j += 8) {
        #pragma unroll
        for (int k = 0; k < 8; ++k) {
            unsigned e = (unsigned)__shfl((int)pkc, j + k);
            gfma(e, lane, mb, acc);
        }
    }

    int t2cnt = min(__shfl(t2l, SEGS), T2CAP);
    if (t2cnt > 0) {
        unsigned pk2 = (lane < t2cnt) ? ell2[(r << 3) + lane] : 0u;
        #pragma unroll
        for (int k = 0; k < 8; ++k) {
            unsigned e = (unsigned)__shfl((int)pk2, k);   // zeros pad -> v=0
            gfma(e, lane, mb, acc);
        }
    }
    ((float4*)(out + ((long long)r << 8)))[lane] = acc;
}

// ---------- overflow edges (tier-3, expected ~0): f32 atomics ----------
__global__ void ovf_kernel(const int* __restrict__ ovfcnt,
                           const OvfEdge* __restrict__ ovf,
                           const float* __restrict__ mat2,
                           float* __restrict__ out) {
    int cnt = min(*ovfcnt, OVFCAP);
    int lane = threadIdx.x & 63;
    int wid = threadIdx.x >> 6;
    for (int e = wid; e < cnt; e += 4) {
        OvfEdge ed = ovf[e];
        float4 m = ((const float4*)(mat2 + (long long)ed.c * F_DIM))[lane];
        float* dst = out + (long long)ed.r * F_DIM + lane * 4;
        unsafeAtomicAdd(dst + 0, ed.v * m.x);
        unsafeAtomicAdd(dst + 1, ed.v * m.y);
        unsafeAtomicAdd(dst + 2, ed.v * m.z);
        unsafeAtomicAdd(dst + 3, ed.v * m.w);
    }
}

// ---------- Path B (R5 fallback): global-cursor ELL ----------
__device__ __forceinline__ void scatter_one(int r, int c, float v,
                                            int* cursor, unsigned* ell,
                                            int* ovfcnt, OvfEdge* ovf) {
    int pos = atomicAdd(&cursor[r], 1);
    if (pos < ELLK) {
        ell[(long long)r * ELLK + pos] = pack_edge(c, v);
    } else {
        int o = atomicAdd(ovfcnt, 1);
        if (o < OVFCAP) { ovf[o].r = r; ovf[o].c = c; ovf[o].v = v; }
    }
}

__global__ void scatter_ell_kernel(const int* __restrict__ rows,
                                   const int* __restrict__ cols,
                                   const float* __restrict__ vals,
                                   int* __restrict__ cursor,
                                   unsigned* __restrict__ ell,
                                   int* __restrict__ ovfcnt,
                                   OvfEdge* __restrict__ ovf, int E) {
    int t = blockIdx.x * blockDim.x + threadIdx.x;
    int i0 = t * 4;
    if (i0 + 3 < E) {
        int4   r = *(const int4*)(rows + i0);
        int4   c = *(const int4*)(cols + i0);
        float4 v = *(const float4*)(vals + i0);
        scatter_one(r.x, c.x, v.x, cursor, ell, ovfcnt, ovf);
        scatter_one(r.y, c.y, v.y, cursor, ell, ovfcnt, ovf);
        scatter_one(r.z, c.z, v.z, cursor, ell, ovfcnt, ovf);
        scatter_one(r.w, c.w, v.w, cursor, ell, ovfcnt, ovf);
    } else {
        for (int i = i0; i < E; ++i)
            scatter_one(rows[i], cols[i], vals[i], cursor, ell, ovfcnt, ovf);
    }
}

template <bool BF16MAT>
__global__ void __launch_bounds__(256)
spmm_ell_kernel(const int* __restrict__ cursor,
                const unsigned* __restrict__ ell,
                const unsigned short* __restrict__ mb,
                const float* __restrict__ mat2,
                float* __restrict__ out, int N) {
    int wave = (int)(((long long)blockIdx.x * blockDim.x + threadIdx.x) >> 6);
    int lane = threadIdx.x & 63;
    if (wave >= N) return;
    int deg = min(cursor[wave], ELLK);
    unsigned pk = (lane < deg) ? ell[(long long)wave * ELLK + lane] : 0u;
    float4 acc = make_float4(0.f, 0.f, 0.f, 0.f);
    int padded = (deg + 7) & ~7;
    for (int j = 0; j < padded; j += 8) {
        #pragma unroll
        for (int k = 0; k < 8; ++k) {
            unsigned e = (unsigned)__shfl((int)pk, j + k);
            int   col = (int)(e >> 16);
            float v   = __uint_as_float((e & 0xFFFFu) << 16);
            if (BF16MAT) {
                ushort4 m = ((const ushort4*)(mb + ((long long)col << 8)))[lane];
                acc.x += v * __uint_as_float((unsigned)m.x << 16);
                acc.y += v * __uint_as_float((unsigned)m.y << 16);
                acc.z += v * __uint_as_float((unsigned)m.z << 16);
                acc.w += v * __uint_as_float((unsigned)m.w << 16);
            } else {
                float4 m = ((const float4*)(mat2 + ((long long)col << 8)))[lane];
                acc.x += v * m.x; acc.y += v * m.y;
                acc.z += v * m.z; acc.w += v * m.w;
            }
        }
    }
    ((float4*)(out + ((long long)wave << 8)))[lane] = acc;
}

// ---------- last resort: pure atomic SpMM ----------
__global__ void spmm_atomic_kernel(const int* __restrict__ rows,
                                   const int* __restrict__ cols,
                                   const float* __restrict__ vals,
                                   const float* __restrict__ mat2,
                                   float* __restrict__ out, int E) {
    long long gid = (long long)blockIdx.x * blockDim.x + threadIdx.x;
    long long e = gid >> 6;
    int q = (int)(gid & 63);
    if (e >= E) return;
    int r = rows[e]; int c = cols[e]; float v = vals[e];
    float4 m = ((const float4*)(mat2 + (long long)c * F_DIM))[q];
    float* dst = out + (long long)r * F_DIM + q * 4;
    unsafeAtomicAdd(dst + 0, v * m.x);
    unsafeAtomicAdd(dst + 1, v * m.y);
    unsafeAtomicAdd(dst + 2, v * m.z);
    unsafeAtomicAdd(dst + 3, v * m.w);
}

extern "C" void kernel_launch(void* const* d_in, const int* in_sizes, int n_in,
                              void* d_out, int out_size, void* d_ws, size_t ws_size,
                              hipStream_t stream) {
    const int*   indices = (const int*)d_in[0];
    const float* vals    = (const float*)d_in[1];
    const float* mat2    = (const float*)d_in[3];
    float*       out     = (float*)d_out;

    const int E  = in_sizes[1];
    const int N  = out_size / F_DIM;
    const int M2 = in_sizes[3];
    const int* rows = indices;
    const int* cols = indices + E;

    auto align16 = [](size_t x) { return (x + 15) & ~(size_t)15; };
    char* ws = (char*)d_ws;

    // ---- Path A layout ----
    size_t o = 0;
    int* cur8   = (int*)(ws + o);                       // 8N
    int* t2cur  = cur8 + (size_t)SEGS * N;              // N
    int* ovfcntA = t2cur + N;                           // 1
    o = align16(o + ((size_t)SEGS * N + N + 1) * 4);
    OvfEdge* ovfA = (OvfEdge*)(ws + o); o = align16(o + (size_t)OVFCAP * sizeof(OvfEdge));
    unsigned* ell1 = (unsigned*)(ws + o); o = align16(o + (size_t)N * ELLK * 4);
    unsigned* ell2 = (unsigned*)(ws + o); o = align16(o + (size_t)N * T2CAP * 4);
    unsigned short* mbA = (unsigned short*)(ws + o); o = align16(o + (size_t)M2 * 2);
    size_t need_A = o;

    // ---- Path B layout ----
    o = 0;
    int* cursor = (int*)(ws + o);
    int* ovfcntB = cursor + N;
    o = align16(o + ((size_t)N + 1) * 4);
    OvfEdge* ovfB = (OvfEdge*)(ws + o); o = align16(o + (size_t)OVFCAP * sizeof(OvfEdge));
    unsigned* ellB = (unsigned*)(ws + o); o = align16(o + (size_t)N * ELLK * 4);
    size_t need_mid = o;
    unsigned short* mbB = (unsigned short*)(ws + o); o = align16(o + (size_t)M2 * 2);
    size_t need_full = o;

    const int vblocks = ((E + 3) / 4 + 255) / 256;   // 4 edges/thread
    const int sblocks = (N * 64 + 255) / 256;        // one wave per row
    const int cblocks = (M2 / 4 + 255) / 256;

    if (N <= 65535 && ws_size >= need_A) {
        hipMemsetAsync(cur8, 0, ((size_t)SEGS * N + N + 1) * 4, stream);
        cvt_kernel<<<cblocks, 256, 0, stream>>>(mat2, mbA, M2 / 4);
        scatter_seg_kernel<<<vblocks, 256, 0, stream>>>(rows, cols, vals, cur8, t2cur,
                                                        ell1, ell2, ovfcntA, ovfA, E, N);
        spmm_seg_kernel<<<sblocks, 256, 0, stream>>>(cur8, t2cur, ell1, ell2, mbA, out, N);
        ovf_kernel<<<1, 256, 0, stream>>>(ovfcntA, ovfA, mat2, out);
    } else if (N <= 65535 && ws_size >= need_full) {
        hipMemsetAsync(cursor, 0, ((size_t)N + 1) * 4, stream);
        cvt_kernel<<<cblocks, 256, 0, stream>>>(mat2, mbB, M2 / 4);
        scatter_ell_kernel<<<vblocks, 256, 0, stream>>>(rows, cols, vals, cursor, ellB, ovfcntB, ovfB, E);
        spmm_ell_kernel<true><<<sblocks, 256, 0, stream>>>(cursor, ellB, mbB, mat2, out, N);
        ovf_kernel<<<1, 256, 0, stream>>>(ovfcntB, ovfB, mat2, out);
    } else if (N <= 65535 && ws_size >= need_mid) {
        hipMemsetAsync(cursor, 0, ((size_t)N + 1) * 4, stream);
        scatter_ell_kernel<<<vblocks, 256, 0, stream>>>(rows, cols, vals, cursor, ellB, ovfcntB, ovfB, E);
        spmm_ell_kernel<false><<<sblocks, 256, 0, stream>>>(cursor, ellB, mbB, mat2, out, N);
        ovf_kernel<<<1, 256, 0, stream>>>(ovfcntB, ovfB, mat2, out);
    } else {
        hipMemsetAsync(d_out, 0, (size_t)out_size * sizeof(float), stream);
        long long total = (long long)E * 64;
        spmm_atomic_kernel<<<(int)((total + 255) / 256), 256, 0, stream>>>(rows, cols, vals, mat2, out, E);
    }
}